// Round 9
// baseline (2945.988 us; speedup 1.0000x reference)
//
#include <hip/hip_runtime.h>

// 5-layer stacked LSTM, T=512 B=256 IN=64 H=128. Storage fp32; internal bf16
// MFMA with fp32 accum (R3 verified, absmax 4.9e-4).
//
// R14: split each layer into GEMM stage (bias + x.W_ih -> fp32 preact ring;
// no serial dep; 16 blocks/layer) and REC stage (h-MFMA onto loaded preact +
// gates; the only serial chain; 16 blocks/layer). 160 blocks / 160 CUs (96KB
// LDS fence -> 1 block/CU, all co-resident). Rationale: R12 ablation showed
// the uncoupled body costs 2990cy (gates 990, gateless floor 2000) -- the
// body's own pipes are the limit, so work must move to OTHER CUs (we used 80
// of 256). x.W_ih is half the MFMAs + half the LDS + all x staging, with no
// serial dependency (the jax reference hoists it too).
//  - preact ring: fp32, lane-major [slot][bg][tid][16] -- gemm lane tid's
//    D-fragment == rec lane tid's (identical 512-thread mapping), no
//    transpose. 8B agent atomics (plain stores would linger in XCD L2).
//  - rec preact: 4-slot register pipeline pg0..3 (static names); load for
//    slot t+4 issued right after body t consumes pg0; drained by a vmcnt(0)
//    +barrier >=1 body later (R9/R10 lessons: never wait a just-issued load,
//    never let counted waits collapse onto fresh export stores).
//  - numerics = R13 exactly (bias -> x-MFMA -> h-MFMA accumulation order).
//  - flag web: pflag(l)=gemm progress, rflag(l)=rec progress. rec(l) needs
//    pflag(l) >= t+5 at issue (gemm leads ~20); gemm(l) needs rflag(l) >=
//    s0-21 (guard, slack 7) and rec(l-1) flag >= s+2 for h tiles. All
//    guards have >=7-slot slack; publishes unconditional -> no deadlock.
// ws hedge: new path needs ~88MB. ws < that -> verified R13 path (863us);
// ws < 16MB -> R3 layer-sequential fallback.

typedef unsigned short ushort_t;
typedef unsigned int uint_t;
typedef unsigned long long ull_t;
typedef __attribute__((ext_vector_type(8))) short short8;
typedef __attribute__((ext_vector_type(4))) float floatx4;
typedef __attribute__((ext_vector_type(2))) float floatx2;

#define T_STEPS 512
#define BATCH   256
#define HID     128
#define NL      5
#define NBG     16
#define RING_R  64
#define PRIME   24
#define FLAG_STRIDE 16
#define SLOT_U  (BATCH * HID / 2)
#define RING_U  ((size_t)RING_R * SLOT_U)
#define WS_NEED (8192 + 4 * RING_U * 4)            // R13 path requirement
#define LDS_BYTES 98304                            // 96KB occupancy fence

// ---- R14 new-path geometry ----
#define HD 32                                      // h-ring depth (slots)
#define PD 32                                      // preact ring depth
#define HSLOT_UL 512                               // ull per bg h tile (4KB)
#define HRING_U ((size_t)HD * 16 * 1024)           // uints per layer h ring
#define PSLOT_F 8192                               // floats per bg preact
#define PRING_F ((size_t)PD * 16 * PSLOT_F)        // floats per layer ring
#define WS2_FLAGS 16384
#define WS2_NEED (WS2_FLAGS + 4 * HRING_U * 4 + 5 * PRING_F * 4)

__device__ __forceinline__ ushort_t f2bf(float f) {
  unsigned int u = __float_as_uint(f);
  u += 0x7FFF + ((u >> 16) & 1);  // RNE; values here are finite
  return (ushort_t)(u >> 16);
}
__device__ __forceinline__ float sigm(float x) {
  float e = __builtin_amdgcn_exp2f(-1.442695041f * x);
  return __builtin_amdgcn_rcpf(1.0f + e);
}
__device__ __forceinline__ float tanh_(float x) {
  float e = __builtin_amdgcn_exp2f(-2.885390082f * x);
  float s = __builtin_amdgcn_rcpf(1.0f + e);
  return __builtin_fmaf(2.0f, s, -1.0f);
}
__device__ __forceinline__ int flag_ld(const int* p) {
  return __hip_atomic_load(p, __ATOMIC_RELAXED, __HIP_MEMORY_SCOPE_AGENT);
}
__device__ __forceinline__ void flag_st(int* p, int v) {
  __hip_atomic_store(p, v, __ATOMIC_RELAXED, __HIP_MEMORY_SCOPE_AGENT);
}
__device__ __forceinline__ ull_t a_ld8(const ull_t* p) {
  return __hip_atomic_load(p, __ATOMIC_RELAXED, __HIP_MEMORY_SCOPE_AGENT);
}
__device__ __forceinline__ void a_st8(ull_t* p, ull_t v) {
  __hip_atomic_store(p, v, __ATOMIC_RELAXED, __HIP_MEMORY_SCOPE_AGENT);
}

__global__ void init_flags(int* flags) {
  int i = blockIdx.x * 256 + threadIdx.x;
  if (i < NL * NBG * FLAG_STRIDE)
    flag_st(&flags[i], 0);
}
__global__ void init_flags2(int* flags) {
  int i = blockIdx.x * 256 + threadIdx.x;
  if (i < 4096) flag_st(&flags[i], 0);
}

// ============================ R14 GEMM stage ================================
// pre[slot s] = bias + x_s . W_ih  (fp32, lane-major fragments).
// my_flag = N <=> preact slots 0..N-1 stored AND drained (publish every 4).
// guard: write slot s only when s - rflag <= PD-8 (clobbers slot s-32;
// rflag >= s-24 => consumed <= s-25... margin 7). upstream (l>0): h slot s
// valid when rec(l-1) flag >= s+1.
template <int KIN, bool SRC_F32>
__device__ __forceinline__ void gemm_stage2(
    unsigned char* lds, const float* xf32, const uint_t* hring_in,
    const float* __restrict__ Wih,
    const float* __restrict__ bih, const float* __restrict__ bhh,
    float* pre_l, int* up_flag, int* guard_flag, int* my_flag, int bg)
{
  constexpr int KX = KIN / 32;
  constexpr int XS = KIN + 8;
  typedef ushort_t (*XT)[16][XS];
  XT Hb = (XT)lds;  // [4][16][XS] input-tile LDS ring (bf16)

  const int tid  = threadIdx.x;
  const int wave = tid >> 6;
  const int lane = tid & 63;
  const int col  = lane & 15;
  const int quad = lane >> 4;
  const int j    = wave * 16 + col;
  const int frow = tid >> 5;
  const int fc   = tid & 31;

  short8 wf[4][KX];
#pragma unroll
  for (int nt = 0; nt < 4; ++nt) {
    int n = nt * 128 + j;
#pragma unroll
    for (int kt = 0; kt < KX; ++kt) {
      const float* p = Wih + n * KIN + kt * 32 + quad * 8;
      short8 w;
#pragma unroll
      for (int e = 0; e < 8; ++e) w[e] = (short)f2bf(p[e]);
      wf[nt][kt] = w;
    }
  }
  float b4[4];
#pragma unroll
  for (int nt = 0; nt < 4; ++nt) b4[nt] = bih[nt * 128 + j] + bhh[nt * 128 + j];

  ull_t hp0 = 0, hp1 = 0;
  floatx2 xp0 = {0.f, 0.f}, xp1 = {0.f, 0.f};

  auto src_load = [&](int s, ull_t& hu, floatx2& xu) {
    if (s < T_STEPS) {
      if constexpr (SRC_F32)
        xu = *(const floatx2*)(xf32 + ((size_t)s * BATCH + bg * 16 + frow) * 64 +
                               fc * 2);
      else
        hu = a_ld8((const ull_t*)(hring_in +
                                  ((size_t)(s & (HD - 1)) * 16 + bg) * 1024) +
                   tid);
    }
  };
  auto commit = [&](int s, ull_t hu, floatx2 xu) {
    if (s < T_STEPS) {
      if constexpr (SRC_F32)
        *(uint_t*)(&Hb[s & 3][frow][fc * 2]) =
            (uint_t)f2bf(xu[0]) | ((uint_t)f2bf(xu[1]) << 16);
      else
        *(ull_t*)(&Hb[s & 3][frow][fc * 4]) = hu;
    }
  };

  int avail = 0;
  auto upwait = [&](int need) {
    if constexpr (!SRC_F32) {
      if (need > T_STEPS) need = T_STEPS;
      if (avail < need) {
        while ((avail = flag_ld(up_flag)) < need) __builtin_amdgcn_s_sleep(1);
      }
      asm volatile("" ::: "memory");
    }
  };

  auto slotbody = [&](int s) {
    short8 af[KX];
#pragma unroll
    for (int kt = 0; kt < KX; ++kt)
      af[kt] = *(const short8*)(&Hb[s & 3][col][kt * 32 + quad * 8]);
    floatx4 pn[4];
#pragma unroll
    for (int nt = 0; nt < 4; ++nt)
      pn[nt] = (floatx4){b4[nt], b4[nt], b4[nt], b4[nt]};
#pragma unroll
    for (int kt = 0; kt < KX; ++kt) {
      short8 a = af[kt];
      pn[0] = __builtin_amdgcn_mfma_f32_16x16x32_bf16(a, wf[0][kt], pn[0], 0, 0, 0);
      pn[1] = __builtin_amdgcn_mfma_f32_16x16x32_bf16(a, wf[1][kt], pn[1], 0, 0, 0);
      pn[2] = __builtin_amdgcn_mfma_f32_16x16x32_bf16(a, wf[2][kt], pn[2], 0, 0, 0);
      pn[3] = __builtin_amdgcn_mfma_f32_16x16x32_bf16(a, wf[3][kt], pn[3], 0, 0, 0);
    }
    ull_t* d = (ull_t*)(pre_l + ((size_t)(s & (PD - 1)) * 16 + bg) * PSLOT_F) +
               tid * 8;
#pragma unroll
    for (int k = 0; k < 8; ++k) {
      ull_t v = (ull_t)__float_as_uint(pn[k >> 1][(k & 1) * 2]) |
                ((ull_t)__float_as_uint(pn[k >> 1][(k & 1) * 2 + 1]) << 32);
      a_st8(d + k, v);
    }
  };

  __syncthreads();

  // prologue: slots 0,1 -> LDS; prefetch 2,3 into regs
  upwait(2);
  {
    ull_t a = 0, b = 0; floatx2 xa = {0.f, 0.f}, xb = {0.f, 0.f};
    src_load(0, a, xa); src_load(1, b, xb);
    commit(0, a, xa);   commit(1, b, xb);   // compiler-counted vmcnt
  }
  upwait(4);
  src_load(2, hp0, xp0); src_load(3, hp1, xp1);
  asm volatile("s_waitcnt lgkmcnt(0)\n\ts_barrier" ::: "memory");

  int rguard = 0;
  for (int sp = 0; sp < 256; ++sp) {
    const int s0 = 2 * sp;
    if ((sp & 1) == 0 && sp) {
      asm volatile("s_waitcnt vmcnt(0)\n\ts_barrier" ::: "memory");
      if (tid == 0) flag_st(my_flag, s0);
      if (s0 + 3 - rguard > PD - 8) {
        while (s0 + 3 - (rguard = flag_ld(guard_flag)) > PD - 8)
          __builtin_amdgcn_s_sleep(1);
        asm volatile("" ::: "memory");
      }
    }
    slotbody(s0);
    slotbody(s0 + 1);
    commit(s0 + 2, hp0, xp0);
    commit(s0 + 3, hp1, xp1);
    upwait(s0 + 6);
    src_load(s0 + 4, hp0, xp0);
    src_load(s0 + 5, hp1, xp1);
    asm volatile("s_waitcnt lgkmcnt(0)\n\ts_barrier" ::: "memory");
  }
  asm volatile("s_waitcnt vmcnt(0)\n\ts_barrier" ::: "memory");
  if (tid == 0) flag_st(my_flag, T_STEPS);
}

// ============================ R14 REC stage =================================
// my_flag = N <=> h-ring slots 0..N-1 stored+drained AND preact slots <=N-1
// consumed. Published every 4 bodies (=t-1). Preact slot u loaded only when
// pflag >= u+1 (mirror + direct-spin fallback). h-ring reuse: export slot s
// (pos s&31, clobbers s-32) only when s - pflag(l+1) <= HD-8.
template <bool RING_OUT>
__device__ __forceinline__ void rec_stage2(
    unsigned char* lds, const float* pre_l, const float* __restrict__ Whh,
    uint_t* ring_out, float* out_f32,
    int* up_flag, int* down_flag, int* my_flag, int bg)
{
  constexpr int HS = 136;
  typedef ushort_t (*HT)[16][HS];
  HT Hr = (HT)lds;  // [2][16][HS]
  int* upm = (int*)(lds + (size_t)2 * 16 * HS * 2);
  int* dnm = upm + 4;

  const int tid  = threadIdx.x;
  const int wave = tid >> 6;
  const int lane = tid & 63;
  const int col  = lane & 15;
  const int quad = lane >> 4;
  const int j    = wave * 16 + col;
  const int frow = tid >> 5;
  const int fc   = tid & 31;

  for (int i = tid; i < 2 * 16 * HS; i += 512) (&Hr[0][0][0])[i] = 0;
  if (tid == 0) {
#pragma unroll
    for (int i = 0; i < 4; ++i) { upm[i] = 0; dnm[i] = 0; }
  }

  short8 wf[4][4];  // Whh fragments only
#pragma unroll
  for (int nt = 0; nt < 4; ++nt) {
    int n = nt * 128 + j;
#pragma unroll
    for (int kt = 0; kt < 4; ++kt) {
      const float* p = Whh + n * 128 + kt * 32 + quad * 8;
      short8 w;
#pragma unroll
      for (int e = 0; e < 8; ++e) w[e] = (short)f2bf(p[e]);
      wf[nt][kt] = w;
    }
  }

  floatx4 c = {0.f, 0.f, 0.f, 0.f};
  int pu = 0, pd = 0;
  floatx4 pg0[4], pg1[4], pg2[4], pg3[4];

  auto load_pg = [&](int u, floatx4 (&p)[4]) {
    const ull_t* p8 =
        (const ull_t*)(pre_l + ((size_t)(u & (PD - 1)) * 16 + bg) * PSLOT_F) +
        tid * 8;
    ull_t v[8];
#pragma unroll
    for (int k = 0; k < 8; ++k) v[k] = a_ld8(p8 + k);
#pragma unroll
    for (int k = 0; k < 8; ++k) {
      p[k >> 1][(k & 1) * 2]     = __uint_as_float((uint_t)v[k]);
      p[k >> 1][(k & 1) * 2 + 1] = __uint_as_float((uint_t)(v[k] >> 32));
    }
  };

  __syncthreads();

  // prologue: lag priming, then slots 0..3 into regs
  {
    int v = 0;
    while ((v = flag_ld(up_flag)) < 12) __builtin_amdgcn_s_sleep(1);
    asm volatile("" ::: "memory");
    if (tid == 0) {
#pragma unroll
      for (int i = 0; i < 4; ++i) upm[i] = v;
      pu = v;
    }
  }
  load_pg(0, pg0); load_pg(1, pg1); load_pg(2, pg2); load_pg(3, pg3);
  asm volatile("s_waitcnt lgkmcnt(0)\n\ts_barrier" ::: "memory");

  auto rbody = [&](int t, floatx4 (&pc)[4]) {
    const int dn = dnm[t & 3];
    if constexpr (RING_OUT) {
      if (t >= 1) {
        const int s = t - 1;
        if (s - dn > HD - 8) {
          while (s - flag_ld(down_flag) > HD - 8) __builtin_amdgcn_s_sleep(1);
          asm volatile("" ::: "memory");
        }
        ull_t h8 = *(const ull_t*)(&Hr[t & 1][frow][fc * 4]);
        a_st8((ull_t*)(ring_out +
                       ((size_t)(s & (HD - 1)) * 16 + bg) * 1024) + tid,
              h8);
      }
    }
    // h-MFMAs onto preloaded preact (critical chain)
#pragma unroll
    for (int kt = 0; kt < 4; ++kt) {
      short8 a = *(const short8*)(&Hr[t & 1][col][kt * 32 + quad * 8]);
      pc[0] = __builtin_amdgcn_mfma_f32_16x16x32_bf16(a, wf[0][kt], pc[0], 0, 0, 0);
      pc[1] = __builtin_amdgcn_mfma_f32_16x16x32_bf16(a, wf[1][kt], pc[1], 0, 0, 0);
      pc[2] = __builtin_amdgcn_mfma_f32_16x16x32_bf16(a, wf[2][kt], pc[2], 0, 0, 0);
      pc[3] = __builtin_amdgcn_mfma_f32_16x16x32_bf16(a, wf[3][kt], pc[3], 0, 0, 0);
    }
    // flag mirrors
    if (tid == 0) {
      upm[(t + 2) & 3] = pu;
      pu = flag_ld(up_flag);
      if constexpr (RING_OUT) {
        dnm[(t + 2) & 3] = pd;
        pd = flag_ld(down_flag);
      }
    }
    // gates
    ushort_t (*wr)[HS] = Hr[(t & 1) ^ 1];
#pragma unroll
    for (int r = 0; r < 4; ++r) {
      float iv = sigm(pc[0][r]);
      float fv = sigm(pc[1][r]);
      float gv = tanh_(pc[2][r]);
      float ov = sigm(pc[3][r]);
      float cn = __builtin_fmaf(fv, c[r], iv * gv);
      c[r] = cn;
      float hv = ov * tanh_(cn);
      wr[quad * 4 + r][j] = f2bf(hv);
      if constexpr (!RING_OUT) {
        out_f32[((size_t)t * BATCH + bg * 16 + quad * 4 + r) * HID + j] = hv;
      }
    }
    asm volatile("s_waitcnt lgkmcnt(0)\n\ts_barrier" ::: "memory");
  };

  auto rissue = [&](int u, floatx4 (&p)[4]) {
    if (u < T_STEPS) {
      const int need = u + 1;
      const int am = upm[u & 3];
      if (am < need) {
        while (flag_ld(up_flag) < need) __builtin_amdgcn_s_sleep(1);
      }
      asm volatile("" ::: "memory");
      load_pg(u, p);
    }
  };

  for (int t = 0; t < T_STEPS; t += 4) {
    // head: drains exports + loads issued >=1 body ago; publish progress
    asm volatile("s_waitcnt vmcnt(0)\n\ts_barrier" ::: "memory");
    if (t && tid == 0) flag_st(my_flag, t - 1);
    rbody(t, pg0);     rissue(t + 4, pg0);
    rbody(t + 1, pg1); rissue(t + 5, pg1);
    asm volatile("s_waitcnt vmcnt(0)\n\ts_barrier" ::: "memory");
    rbody(t + 2, pg2); rissue(t + 6, pg2);
    rbody(t + 3, pg3); rissue(t + 7, pg3);
  }
  asm volatile("s_waitcnt vmcnt(0)\n\ts_barrier" ::: "memory");
  if (tid == 0) flag_st(my_flag, T_STEPS);
}

// stage mapping: blockIdx = stage*16+bg; stage 2l = gemm(l), 2l+1 = rec(l)
__global__ __launch_bounds__(512) void lstm_pipe2(
    const float* x, const float* Wih0, const float* WihR,
    const float* Whh, const float* bih, const float* bhh,
    float* out, uint_t* hring, float* pre, int* flags)
{
  __shared__ __align__(16) unsigned char lds_raw[LDS_BYTES];
  const int stage = blockIdx.x >> 4;
  const int bg    = blockIdx.x & 15;
  const int l     = stage >> 1;
  int* fl = flags;
  auto fidx = [&](int st) { return fl + (st * 16 + bg) * FLAG_STRIDE; };

  if ((stage & 1) == 0) {  // GEMM(l)
    float* pre_l = pre + (size_t)l * PRING_F;
    int* mine  = fidx(2 * l);
    int* guard = fidx(2 * l + 1);                 // rec(l) progress
    if (l == 0) {
      gemm_stage2<64, true>(lds_raw, x, nullptr, Wih0, bih, bhh,
                            pre_l, nullptr, guard, mine, bg);
    } else {
      gemm_stage2<128, false>(lds_raw, nullptr,
                              hring + (size_t)(l - 1) * HRING_U,
                              WihR + (size_t)(l - 1) * 512 * 128,
                              bih + l * 512, bhh + l * 512,
                              pre_l, fidx(2 * (l - 1) + 1), guard, mine, bg);
    }
  } else {  // REC(l)
    const float* pre_l = pre + (size_t)l * PRING_F;
    int* mine = fidx(2 * l + 1);
    int* up   = fidx(2 * l);
    if (l < 4) {
      rec_stage2<true>(lds_raw, pre_l, Whh + (size_t)l * 512 * 128,
                       hring + (size_t)l * HRING_U, nullptr,
                       up, fidx(2 * (l + 1)), mine, bg);
    } else {
      rec_stage2<false>(lds_raw, pre_l, Whh + (size_t)4 * 512 * 128,
                        nullptr, out, up, nullptr, mine, bg);
    }
  }
}

// =========================== R13 path (verified, hedge) =====================
__device__ __forceinline__ ull_t ring_ld8(const uint_t* base, int tid) {
  return a_ld8((const ull_t*)base + tid);
}
__device__ __forceinline__ void ring_st8(uint_t* base, int tid, ull_t v) {
  a_st8((ull_t*)base + tid, v);
}

template <int KIN, bool SRC_F32, bool RING_OUT>
__device__ __forceinline__ void lstm_stage(
    unsigned char* lds,
    const float* xf32, const uint_t* ring_in,
    const float* __restrict__ Wih, const float* __restrict__ Whh,
    const float* __restrict__ bih, const float* __restrict__ bhh,
    uint_t* ring_out, float* out_f32,
    int* up_flag, int* down_flag, int* my_flag, int bg)
{
  constexpr int KX = KIN / 32;
  constexpr int XS = KIN + 8;
  constexpr int HS = 128 + 8;

  typedef ushort_t (*XT)[16][XS];
  typedef ushort_t (*HT)[16][HS];
  XT Xr = (XT)lds;
  HT Hr = (HT)(lds + (size_t)8 * 16 * XS * 2);
  int* upm = (int*)(lds + (size_t)8 * 16 * XS * 2 + (size_t)2 * 16 * HS * 2);
  int* dnm = upm + 4;

  const int tid  = threadIdx.x;
  const int wave = tid >> 6;
  const int lane = tid & 63;
  const int col  = lane & 15;
  const int quad = lane >> 4;
  const int j    = wave * 16 + col;
  const int frow = tid >> 5;
  const int fc   = tid & 31;

  for (int i = tid; i < 2 * 16 * HS; i += 512) (&Hr[0][0][0])[i] = 0;
  if (tid == 0) {
#pragma unroll
    for (int i = 0; i < 4; ++i) { upm[i] = 0; dnm[i] = 0; }
  }

  short8 wf[4][KX + 4];
#pragma unroll
  for (int nt = 0; nt < 4; ++nt) {
    int n = nt * 128 + j;
#pragma unroll
    for (int kt = 0; kt < KX; ++kt) {
      const float* p = Wih + n * KIN + kt * 32 + quad * 8;
      short8 w;
#pragma unroll
      for (int e = 0; e < 8; ++e) w[e] = (short)f2bf(p[e]);
      wf[nt][kt] = w;
    }
#pragma unroll
    for (int kt = 0; kt < 4; ++kt) {
      const float* p = Whh + n * 128 + kt * 32 + quad * 8;
      short8 w;
#pragma unroll
      for (int e = 0; e < 8; ++e) w[e] = (short)f2bf(p[e]);
      wf[nt][KX + kt] = w;
    }
  }
  const float bi  = bih[j]       + bhh[j];
  const float bf_ = bih[128 + j] + bhh[128 + j];
  const float bgi = bih[256 + j] + bhh[256 + j];
  const float bo  = bih[384 + j] + bhh[384 + j];

  floatx4 c = {0.f, 0.f, 0.f, 0.f};
  int pu = 0, pd = 0;
  ull_t  pf4[4];
  floatx2 px4[4];
  floatx4 pA[4], pB[4];

  __syncthreads();

  if constexpr (!SRC_F32) {
    int v = 0;
    while ((v = flag_ld(up_flag)) < PRIME) __builtin_amdgcn_s_sleep(1);
    asm volatile("" ::: "memory");
    if (tid == 0) {
#pragma unroll
      for (int i = 0; i < 4; ++i) upm[i] = v;
      pu = v;
    }
    ull_t pr[8];
#pragma unroll
    for (int s = 0; s < 8; ++s)
      pr[s] = ring_ld8(ring_in + (size_t)s * SLOT_U + bg * 1024, tid);
#pragma unroll
    for (int s = 0; s < 8; ++s)
      *(ull_t*)(&Xr[s][frow][fc * 4]) = pr[s];
  } else {
    floatx2 pr[8];
#pragma unroll
    for (int s = 0; s < 8; ++s)
      pr[s] = *(const floatx2*)(xf32 +
                                ((size_t)s * BATCH + bg * 16 + frow) * 64 +
                                fc * 2);
#pragma unroll
    for (int s = 0; s < 8; ++s)
      *(uint_t*)(&Xr[s][frow][fc * 2]) =
          (uint_t)f2bf(pr[s][0]) | ((uint_t)f2bf(pr[s][1]) << 16);
  }
  asm volatile("s_waitcnt lgkmcnt(0)\n\ts_barrier" ::: "memory");

  pA[0] = (floatx4){bi, bi, bi, bi};
  pA[1] = (floatx4){bf_, bf_, bf_, bf_};
  pA[2] = (floatx4){bgi, bgi, bgi, bgi};
  pA[3] = (floatx4){bo, bo, bo, bo};
#pragma unroll
  for (int kt = 0; kt < KX; ++kt) {
    short8 ax = *(const short8*)(&Xr[0][col][kt * 32 + quad * 8]);
    pA[0] = __builtin_amdgcn_mfma_f32_16x16x32_bf16(ax, wf[0][kt], pA[0], 0, 0, 0);
    pA[1] = __builtin_amdgcn_mfma_f32_16x16x32_bf16(ax, wf[1][kt], pA[1], 0, 0, 0);
    pA[2] = __builtin_amdgcn_mfma_f32_16x16x32_bf16(ax, wf[2][kt], pA[2], 0, 0, 0);
    pA[3] = __builtin_amdgcn_mfma_f32_16x16x32_bf16(ax, wf[3][kt], pA[3], 0, 0, 0);
  }

  auto body = [&](int t, floatx4 (&pc)[4], floatx4 (&pn)[4]) {
    if ((t & 3) == 0) {
      if (t >= 4) {
        asm volatile("s_waitcnt vmcnt(0)\n\ts_barrier" ::: "memory");
        if (tid == 0) flag_st(my_flag, t - 1);
#pragma unroll
        for (int g = 0; g < 4; ++g) {
          const int s = t + 4 + g;
          if (s < T_STEPS) {
            if constexpr (SRC_F32)
              *(uint_t*)(&Xr[s & 7][frow][fc * 2]) =
                  (uint_t)f2bf(px4[g][0]) | ((uint_t)f2bf(px4[g][1]) << 16);
            else
              *(ull_t*)(&Xr[s & 7][frow][fc * 4]) = pf4[g];
          }
        }
      }
      if (t + 8 < T_STEPS) {
        if constexpr (!SRC_F32) {
          int need = t + 12;
          if (need > T_STEPS) need = T_STEPS;
          if (upm[t & 3] < need) {
            while (flag_ld(up_flag) < need) __builtin_amdgcn_s_sleep(1);
          }
        }
        asm volatile("" ::: "memory");
#pragma unroll
        for (int g = 0; g < 4; ++g) {
          const int s = t + 8 + g;
          if (s < T_STEPS) {
            if constexpr (SRC_F32)
              px4[g] = *(const floatx2*)(
                  xf32 + ((size_t)s * BATCH + bg * 16 + frow) * 64 + fc * 2);
            else
              pf4[g] = ring_ld8(
                  ring_in + (size_t)(s & (RING_R - 1)) * SLOT_U + bg * 1024,
                  tid);
          }
        }
      }
    }
    const int dn = dnm[t & 3];

    if constexpr (RING_OUT) {
      if (t >= 1) {
        const int s = t - 1;
        if (s - dn > RING_R - 16) {
          while (s - flag_ld(down_flag) > RING_R - 16)
            __builtin_amdgcn_s_sleep(1);
          asm volatile("" ::: "memory");
        }
        ull_t h8 = *(const ull_t*)(&Hr[t & 1][frow][fc * 4]);
        ring_st8(ring_out + (size_t)(s & (RING_R - 1)) * SLOT_U + bg * 1024,
                 tid, h8);
      }
    }

#pragma unroll
    for (int kt = 0; kt < 4; ++kt) {
      short8 a = *(const short8*)(&Hr[t & 1][col][kt * 32 + quad * 8]);
      pc[0] = __builtin_amdgcn_mfma_f32_16x16x32_bf16(a, wf[0][KX + kt], pc[0], 0, 0, 0);
      pc[1] = __builtin_amdgcn_mfma_f32_16x16x32_bf16(a, wf[1][KX + kt], pc[1], 0, 0, 0);
      pc[2] = __builtin_amdgcn_mfma_f32_16x16x32_bf16(a, wf[2][KX + kt], pc[2], 0, 0, 0);
      pc[3] = __builtin_amdgcn_mfma_f32_16x16x32_bf16(a, wf[3][KX + kt], pc[3], 0, 0, 0);
    }

    if (t + 1 < T_STEPS) {
      pn[0] = (floatx4){bi, bi, bi, bi};
      pn[1] = (floatx4){bf_, bf_, bf_, bf_};
      pn[2] = (floatx4){bgi, bgi, bgi, bgi};
      pn[3] = (floatx4){bo, bo, bo, bo};
#pragma unroll
      for (int kt = 0; kt < KX; ++kt) {
        short8 ax = *(const short8*)(&Xr[(t + 1) & 7][col][kt * 32 + quad * 8]);
        pn[0] = __builtin_amdgcn_mfma_f32_16x16x32_bf16(ax, wf[0][kt], pn[0], 0, 0, 0);
        pn[1] = __builtin_amdgcn_mfma_f32_16x16x32_bf16(ax, wf[1][kt], pn[1], 0, 0, 0);
        pn[2] = __builtin_amdgcn_mfma_f32_16x16x32_bf16(ax, wf[2][kt], pn[2], 0, 0, 0);
        pn[3] = __builtin_amdgcn_mfma_f32_16x16x32_bf16(ax, wf[3][kt], pn[3], 0, 0, 0);
      }
    }

    if (tid == 0) {
      if constexpr (!SRC_F32) {
        upm[(t + 2) & 3] = pu;
        pu = flag_ld(up_flag);
      }
      if constexpr (RING_OUT) {
        dnm[(t + 2) & 3] = pd;
        pd = flag_ld(down_flag);
      }
    }

    ushort_t (*wr)[HS] = Hr[(t & 1) ^ 1];
#pragma unroll
    for (int r = 0; r < 4; ++r) {
      float iv = sigm(pc[0][r]);
      float fv = sigm(pc[1][r]);
      float gv = tanh_(pc[2][r]);
      float ov = sigm(pc[3][r]);
      float cn = __builtin_fmaf(fv, c[r], iv * gv);
      c[r] = cn;
      float hv = ov * tanh_(cn);
      wr[quad * 4 + r][j] = f2bf(hv);
      if constexpr (!RING_OUT) {
        out_f32[((size_t)t * BATCH + bg * 16 + quad * 4 + r) * HID + j] = hv;
      }
    }

    asm volatile("s_waitcnt lgkmcnt(0)\n\ts_barrier" ::: "memory");
  };

  for (int t = 0; t < T_STEPS; t += 2) {
    body(t, pA, pB);
    body(t + 1, pB, pA);
  }

  if constexpr (RING_OUT) {
    const int s = T_STEPS - 1;
    while (s - flag_ld(down_flag) > RING_R - 16) __builtin_amdgcn_s_sleep(1);
    asm volatile("" ::: "memory");
    ull_t h8 = *(const ull_t*)(&Hr[T_STEPS & 1][frow][fc * 4]);
    ring_st8(ring_out + (size_t)(s & (RING_R - 1)) * SLOT_U + bg * 1024, tid,
             h8);
  }
  asm volatile("s_waitcnt vmcnt(0)\n\ts_barrier" ::: "memory");
  if (tid == 0) flag_st(my_flag, T_STEPS);
}

__global__ __launch_bounds__(512) void lstm_pipe(
    const float* x, const float* Wih0, const float* WihR,
    const float* Whh, const float* bih, const float* bhh,
    float* out, uint_t* ring, int* flags)
{
  __shared__ __align__(16) unsigned char lds_raw[LDS_BYTES];
  const int l  = blockIdx.x >> 4;
  const int bg = blockIdx.x & 15;
  int* mine = flags + (l * NBG + bg) * FLAG_STRIDE;
  int* up   = (l > 0) ? flags + ((l - 1) * NBG + bg) * FLAG_STRIDE : nullptr;
  int* down = (l < 4) ? flags + ((l + 1) * NBG + bg) * FLAG_STRIDE : nullptr;

  if (l == 0) {
    lstm_stage<64, true, true>(lds_raw, x, nullptr, Wih0, Whh, bih, bhh,
                               ring, nullptr, up, down, mine, bg);
  } else if (l < 4) {
    lstm_stage<128, false, true>(lds_raw, nullptr,
                                 ring + (size_t)(l - 1) * RING_U,
                                 WihR + (size_t)(l - 1) * 512 * 128,
                                 Whh + (size_t)l * 512 * 128,
                                 bih + l * 512, bhh + l * 512,
                                 ring + (size_t)l * RING_U, nullptr,
                                 up, down, mine, bg);
  } else {
    lstm_stage<128, false, false>(lds_raw, nullptr,
                                  ring + (size_t)3 * RING_U,
                                  WihR + (size_t)3 * 512 * 128,
                                  Whh + (size_t)4 * 512 * 128,
                                  bih + 4 * 512, bhh + 4 * 512,
                                  nullptr, out, up, nullptr, mine, bg);
  }
}

// ------------------------------------------------- fallback (R3, verified) --
template <int KIN>
__global__ __launch_bounds__(512) void lstm_layer(
    const float* xin, float* hout,
    const float* __restrict__ Wih, const float* __restrict__ Whh,
    const float* __restrict__ bih, const float* __restrict__ bhh)
{
  constexpr int KX = KIN / 32, KT = KX + 4;
  constexpr int AW = KIN + 128, AS = AW + 8;
  constexpr int NSTG = 16 * KIN / 4;

  const int bg = blockIdx.x, tid = threadIdx.x;
  const int wave = tid >> 6, lane = tid & 63;
  const int col = lane & 15, quad = lane >> 4;
  const int j = wave * 16 + col;

  __shared__ __align__(16) ushort_t Ah[2][16][AS];
  for (int i = tid; i < 2 * 16 * AS; i += 512) (&Ah[0][0][0])[i] = 0;

  short8 wf[4][KT];
#pragma unroll
  for (int nt = 0; nt < 4; ++nt) {
    int n = nt * 128 + j;
#pragma unroll
    for (int kt = 0; kt < KX; ++kt) {
      const float* p = Wih + n * KIN + kt * 32 + quad * 8;
      short8 w;
#pragma unroll
      for (int e = 0; e < 8; ++e) w[e] = (short)f2bf(p[e]);
      wf[nt][kt] = w;
    }
#pragma unroll
    for (int kt = 0; kt < 4; ++kt) {
      const float* p = Whh + n * 128 + kt * 32 + quad * 8;
      short8 w;
#pragma unroll
      for (int e = 0; e < 8; ++e) w[e] = (short)f2bf(p[e]);
      wf[nt][KX + kt] = w;
    }
  }
  const float bi  = bih[j]       + bhh[j];
  const float bf_ = bih[128 + j] + bhh[128 + j];
  const float bgi = bih[256 + j] + bhh[256 + j];
  const float bo  = bih[384 + j] + bhh[384 + j];

  floatx4 c = {0.f, 0.f, 0.f, 0.f};
  const int srow = tid / (KIN / 4), scol = (tid % (KIN / 4)) * 4;
  floatx4 xv = {0.f, 0.f, 0.f, 0.f};
  auto stage_load = [&](int t) {
    if (tid < NSTG && t < T_STEPS)
      xv = *(const floatx4*)(xin + (size_t)(t * BATCH + bg * 16 + srow) * KIN + scol);
  };
  auto stage_store = [&](int t, ushort_t (*buf)[AS]) {
    if (tid < NSTG && t < T_STEPS) {
#pragma unroll
      for (int e = 0; e < 4; ++e) buf[srow][scol + e] = f2bf(xv[e]);
    }
  };
  __syncthreads();
  stage_load(0); stage_store(0, Ah[0]); stage_load(1);
  __syncthreads();

  for (int t = 0; t < T_STEPS; ++t) {
    ushort_t (*rd)[AS] = Ah[t & 1];
    ushort_t (*wr)[AS] = Ah[(t & 1) ^ 1];
    short8 af[KT];
#pragma unroll
    for (int kt = 0; kt < KT; ++kt)
      af[kt] = *(const short8*)(&rd[col][kt * 32 + quad * 8]);
    floatx4 a0 = {0, 0, 0, 0}, a1 = {0, 0, 0, 0}, a2 = {0, 0, 0, 0},
            a3 = {0, 0, 0, 0};
#pragma unroll
    for (int kt = 0; kt < KT; ++kt) {
      short8 a = af[kt];
      a0 = __builtin_amdgcn_mfma_f32_16x16x32_bf16(a, wf[0][kt], a0, 0, 0, 0);
      a1 = __builtin_amdgcn_mfma_f32_16x16x32_bf16(a, wf[1][kt], a1, 0, 0, 0);
      a2 = __builtin_amdgcn_mfma_f32_16x16x32_bf16(a, wf[2][kt], a2, 0, 0, 0);
      a3 = __builtin_amdgcn_mfma_f32_16x16x32_bf16(a, wf[3][kt], a3, 0, 0, 0);
    }
    stage_store(t + 1, wr);
    stage_load(t + 2);
    size_t obase = (size_t)(t * BATCH + bg * 16) * HID + j;
#pragma unroll
    for (int r = 0; r < 4; ++r) {
      int row = quad * 4 + r;
      float iv = sigm(a0[r] + bi);
      float fv = sigm(a1[r] + bf_);
      float gv = tanh_(a2[r] + bgi);
      float ov = sigm(a3[r] + bo);
      float cn = __builtin_fmaf(fv, c[r], iv * gv);
      c[r] = cn;
      float hv = ov * tanh_(cn);
      wr[row][KIN + j] = f2bf(hv);
      hout[obase + (size_t)row * HID] = hv;
    }
    __syncthreads();
  }
}

extern "C" void kernel_launch(void* const* d_in, const int* in_sizes, int n_in,
                              void* d_out, int out_size, void* d_ws,
                              size_t ws_size, hipStream_t stream) {
  const float* x    = (const float*)d_in[0];  // [512,256,64]
  const float* Wih0 = (const float*)d_in[1];  // [512,64]
  const float* WihR = (const float*)d_in[2];  // [4,512,128]
  const float* Whh  = (const float*)d_in[3];  // [5,512,128]
  const float* bih  = (const float*)d_in[4];  // [5,512]
  const float* bhh  = (const float*)d_in[5];  // [5,512]
  float* out = (float*)d_out;                 // [512,256,128]

  if (ws_size >= WS2_NEED) {
    // R14 path: gemm/rec split, 160 blocks
    int* flags = (int*)d_ws;
    uint_t* hring = (uint_t*)((char*)d_ws + WS2_FLAGS);
    float* pre = (float*)((char*)d_ws + WS2_FLAGS + 4 * HRING_U * 4);
    init_flags2<<<16, 256, 0, stream>>>(flags);
    lstm_pipe2<<<160, 512, 0, stream>>>(x, Wih0, WihR, Whh, bih, bhh,
                                        out, hring, pre, flags);
  } else if (ws_size >= WS_NEED) {
    // R13 path (verified)
    int* flags = (int*)d_ws;
    uint_t* ring = (uint_t*)((char*)d_ws + 8192);
    init_flags<<<(NL * NBG * FLAG_STRIDE + 255) / 256, 256, 0, stream>>>(flags);
    lstm_pipe<<<NL * NBG, 512, 0, stream>>>(x, Wih0, WihR, Whh, bih, bhh,
                                            out, ring, flags);
  } else {
    lstm_layer<64><<<16, 512, 0, stream>>>(x, out, Wih0, Whh, bih, bhh);
    for (int l = 1; l < 5; ++l)
      lstm_layer<128><<<16, 512, 0, stream>>>(
          out, out, WihR + (size_t)(l - 1) * 512 * 128,
          Whh + (size_t)l * 512 * 128, bih + l * 512, bhh + l * 512);
  }
}